// Round 3
// baseline (941.674 us; speedup 1.0000x reference)
//
#include <hip/hip_runtime.h>

// Problem constants
#define N_VERT 5000
#define NCOL   12288      // B*T*C_OUT reinterpreted columns
#define KPAD   5056       // 158*32: K padded (zero-filled)
#define MPAD   5120       // 40*128: M padded

#define G1_BLOCKS  15168  // 79*192 gemm1 blocks
#define CVT_BLOCKS 25280  // MPAD*(KPAD/4)/256

typedef float          f32x4  __attribute__((ext_vector_type(4)));
typedef unsigned short u16x4  __attribute__((ext_vector_type(4)));
typedef __bf16         bf16x8 __attribute__((ext_vector_type(8)));

__device__ __forceinline__ unsigned short f2bf(float f) {
  unsigned int u = __builtin_bit_cast(unsigned int, f);
  u += 0x7fffu + ((u >> 16) & 1u);   // RNE
  return (unsigned short)(u >> 16);
}

__device__ __forceinline__ void async16(const unsigned short* g, unsigned short* l) {
  __builtin_amdgcn_global_load_lds(
      (const __attribute__((address_space(1))) unsigned int*)g,
      (__attribute__((address_space(3))) unsigned int*)l, 16, 0, 0);
}

// ---------------------------------------------------------------------------
// Kernel P (merged prep): blocks [0, G1_BLOCKS) run GEMM1 (x@W -> Ht = H^T,
// bf16); blocks [G1_BLOCKS, +CVT_BLOCKS) convert F -> Fb bf16 [MPAD][KPAD].
// ---------------------------------------------------------------------------
__global__ __launch_bounds__(256) void prep(const float* __restrict__ x,
                                            const float* __restrict__ W,
                                            const float* __restrict__ F,
                                            unsigned short* __restrict__ Ht,
                                            unsigned short* __restrict__ Fb) {
  __shared__ float xt[64][68];
  __shared__ float Wl[64][68];
  const int tid = threadIdx.x;

  if (blockIdx.x >= G1_BLOCKS) {
    int idx = (blockIdx.x - G1_BLOCKS) * 256 + tid;
    int row = idx / (KPAD / 4);
    int c4  = (idx % (KPAD / 4)) * 4;
    u16x4 o;
    if (row < N_VERT && c4 < N_VERT) {
      f32x4 v = *(const f32x4*)(F + (long)row * N_VERT + c4);
      o.x = f2bf(v.x); o.y = f2bf(v.y); o.z = f2bf(v.z); o.w = f2bf(v.w);
    } else {
      o.x = 0; o.y = 0; o.z = 0; o.w = 0;
    }
    *(u16x4*)(Fb + (long)row * KPAD + c4) = o;
    return;
  }

  const int utile = blockIdx.x % 79;   // 0..78
  const int rr    = blockIdx.x / 79;   // 0..191

  for (int i = tid; i < 4096; i += 256) Wl[i >> 6][i & 63] = W[i];
  {
    int rowu = tid >> 2;
    int cb   = (tid & 3) * 16;
    long u   = (long)utile * 64 + rowu;
    bool valid = (u < N_VERT);
    const float* src = x + (u * 192 + rr) * 64;
#pragma unroll
    for (int q = 0; q < 4; ++q) {
      int col = cb + q * 4;
      f32x4 v = {0.f, 0.f, 0.f, 0.f};
      if (valid) v = *(const f32x4*)(src + col);
      xt[col + 0][rowu] = v.x;
      xt[col + 1][rowu] = v.y;
      xt[col + 2][rowu] = v.z;
      xt[col + 3][rowu] = v.w;
    }
  }
  __syncthreads();

  const int ul0 = (tid & 15) * 4;
  const int j0  = (tid >> 4) * 4;
  float acc[4][4] = {};
#pragma unroll 8
  for (int c = 0; c < 64; ++c) {
    f32x4 xv = *(const f32x4*)&xt[c][ul0];
    f32x4 wv = *(const f32x4*)&Wl[c][j0];
#pragma unroll
    for (int a = 0; a < 4; ++a)
#pragma unroll
      for (int b = 0; b < 4; ++b) acc[a][b] += xv[a] * wv[b];
  }

  long ug = (long)utile * 64 + ul0;
#pragma unroll
  for (int b = 0; b < 4; ++b) {
    long rowh = (long)rr * 64 + (j0 + b);
    u16x4 o = {f2bf(acc[0][b]), f2bf(acc[1][b]), f2bf(acc[2][b]), f2bf(acc[3][b])};
    *(u16x4*)(Ht + rowh * KPAD + ug) = o;
  }
}

// ---------------------------------------------------------------------------
// Kernel 3: GEMM2  agg = F @ H (+bias).
// *** 128x256 tile, BK=32, 256 threads (4 waves, 1M x 4N), LDS 48KiB ->
// 2 co-resident blocks/CU (two independent barrier domains per CU; each SIMD
// hosts one wave of each domain, so one block's barrier/vmcnt stalls overlap
// the other block's MFMA). Same verified 3-phase R0 schedule, halved:
//  PH0: read afL(m0..3) + bb[2..3](t); 16 MFMA afL x bb[0..3]; bar
//  PH1: read afH(m4..7); stage B(t+2); 8 MFMA afH x bb[0..1]; bar
//  PH2: stage A(t+2); vmcnt(6); bar; cross-read bb[0..1](t+1); 8 MFMA afH x bb[2..3]
// BK=32 => 64B LDS rows: fragment read (16 rows x 4 chunks, chunk = l>>4) is
// exactly bank-balanced (8 dwords/bank) with NO swizzle; staging is linear
// DMA on both sides (global source linear, LDS dest linear).
// Hazards (same invariants as R0): B(bi) last read PH0, staged PH1 (after
// PH0-end barrier); A(bi) last read PH1, staged PH2; cross-read of t+1's B
// after vmcnt(6)+barrier (the 6 newest outstanding = t+2's own 6 loads, so
// all of t+1's have retired). Drain tile uses vmcnt(0); tail has no stage.
// Per wave/tile: 12 ds_read_b128, 32 MFMA, 6 DMA loads.
// ---------------------------------------------------------------------------
__global__ __launch_bounds__(256, 2) void gemm2(const unsigned short* __restrict__ A,
                                                const unsigned short* __restrict__ Bt,
                                                const float* __restrict__ bias,
                                                float* __restrict__ out) {
  __shared__ __align__(16) unsigned short smem[24576];   // 49152 B = 2 x (A 8K + B 16K)
  char* sm = (char*)smem;

  const int tid = threadIdx.x;
  const int l   = tid & 63;
  const int w   = tid >> 6;        // wave 0..3 = N-quarter (wc)
  const int la  = l & 15;

  // Block mapping: 1920 blocks = 8 xcd x 5 mloc x 48 n (bijective).
  // Per XCD: one 128-row A strip (1.3MB, L2-resident) walks all 48 N tiles.
  const int xcd  = blockIdx.x & 7;
  const int ii   = blockIdx.x >> 3;    // 0..239
  const int mloc = ii / 48;            // 0..4
  const int nt   = ii % 48;
  const long tM  = (long)(xcd * 5 + mloc) * 128;
  const long tN  = (long)nt * 256;

  // --- staging source (linear: lane covers row l>>2, 16B chunk l&3) ---
  const unsigned short* gA2 = A  + (tM + (l >> 2)) * (size_t)KPAD + (l & 3) * 8;
  const unsigned short* gB2 = Bt + (tN + (l >> 2)) * (size_t)KPAD + (l & 3) * 8;

  // A region [0,8192): 128 rows x 64B. B region [8192,24576): 256 rows x 64B.
  auto stageA = [&](int bufB, const unsigned short* g) {
    async16(g + (size_t)(w * 16)      * KPAD, (unsigned short*)(sm + bufB + w * 1024));
    async16(g + (size_t)(w * 16 + 64) * KPAD, (unsigned short*)(sm + bufB + w * 1024 + 4096));
  };
  auto stageB = [&](int bufB, const unsigned short* g) {
#pragma unroll
    for (int q = 0; q < 4; ++q)
      async16(g + (size_t)(w * 16 + q * 64) * KPAD,
              (unsigned short*)(sm + bufB + 8192 + w * 1024 + q * 4096));
  };

  // --- read base pointers (row-major 64B rows; lane reads chunk l>>4) ---
  const int lofs = la * 64 + (l >> 4) * 16;
  const char* pA[2] = { sm + lofs,                   sm + 24576 + lofs };
  const char* pB[2] = { sm + 8192 + w * 4096 + lofs, sm + 24576 + 8192 + w * 4096 + lofs };

  f32x4  acc[8][4] = {};
  bf16x8 af[4], bb[4];

#define MM(MBASE, NLO, NHI)                                                   \
  __builtin_amdgcn_s_setprio(1);                                             \
  _Pragma("unroll")                                                          \
  for (int m = 0; m < 4; ++m)                                                \
    _Pragma("unroll")                                                        \
    for (int n = (NLO); n < (NHI); ++n)                                      \
      acc[(MBASE) + m][n] = __builtin_amdgcn_mfma_f32_16x16x32_bf16(         \
          af[m], bb[n], acc[(MBASE) + m][n], 0, 0, 0);                       \
  __builtin_amdgcn_s_setprio(0);

  // mode: 0 steady; 1 = drain (no stage, vmcnt(0)); 2 = tail (no stage/cross).
  auto tile = [&](int bi, int mode) {
    const int bo = bi * 24576;
    const int ni = bi ^ 1;
    // ==== PH0: read afL + bb[2..3](t); 16 MFMA afL x bb[0..3] ====
#pragma unroll
    for (int m = 0; m < 4; ++m) af[m] = *(const bf16x8*)(pA[bi] + m * 1024);
    bb[2] = *(const bf16x8*)(pB[bi] + 2 * 1024);
    bb[3] = *(const bf16x8*)(pB[bi] + 3 * 1024);
    MM(0, 0, 4)
    __builtin_amdgcn_s_barrier();
    // ==== PH1: read afH; stage B(t+2); 8 MFMA afH x bb[0..1] ====
#pragma unroll
    for (int m = 0; m < 4; ++m) af[m] = *(const bf16x8*)(pA[bi] + (4 + m) * 1024);
    if (mode == 0) { stageB(bo, gB2); gB2 += 32; }
    MM(4, 0, 2)
    __builtin_amdgcn_s_barrier();
    // ==== PH2: stage A(t+2); vmcnt(6); bar; cross-read bb[0..1](t+1); 8 MFMA ====
    if (mode == 0) {
      stageA(bo, gA2); gA2 += 32;
      asm volatile("s_waitcnt vmcnt(6)" ::: "memory");   // t+1 fully landed
    } else if (mode == 1) {
      asm volatile("s_waitcnt vmcnt(0)" ::: "memory");
    }
    __builtin_amdgcn_s_barrier();                         // globalizes vmcnt
    __builtin_amdgcn_sched_barrier(0);                    // pin reads below
    if (mode != 2) {
      bb[0] = *(const bf16x8*)(pB[ni] + 0);               // bb[0..1](t+1)
      bb[1] = *(const bf16x8*)(pB[ni] + 1024);
    }
    MM(4, 2, 4)
    // no trailing barrier: next PH0's reads are covered by this vmcnt+bar
  };

  // ---- prologue: stage t0 -> buf0, t1 -> buf1; pre-read bb[0..1](t0) ----
  stageB(0, gB2);     stageA(0, gA2);     gA2 += 32; gB2 += 32;
  stageB(24576, gB2); stageA(24576, gA2); gA2 += 32; gB2 += 32;  // -> t2
  asm volatile("s_waitcnt vmcnt(6)" ::: "memory");   // t0's 6 loads landed
  __builtin_amdgcn_s_barrier();
  __builtin_amdgcn_sched_barrier(0);
  bb[0] = *(const bf16x8*)(pB[0] + 0);
  bb[1] = *(const bf16x8*)(pB[0] + 1024);

  // ---- main loop: 158 K-tiles (t = 0..157) ----
#pragma unroll 1
  for (int it = 0; it < 77; ++it) {    // t = 0..153
    tile(0, 0);
    tile(1, 0);
  }
  tile(0, 0);   // t=154: stages t156 -> buf0
  tile(1, 0);   // t=155: stages t157 -> buf1
  tile(0, 1);   // t=156: drain, cross-read bb(t157) from buf1
  tile(1, 2);   // t=157: last

#undef MM

  // ---- epilogue: C/D map col=lane&15, row=(lane>>4)*4+reg ----
  float bv[4];
#pragma unroll
  for (int n = 0; n < 4; ++n) bv[n] = bias[n * 16 + la];
  const int rb = (l >> 4) * 4;
#pragma unroll
  for (int m = 0; m < 8; ++m) {
    long gm0 = tM + m * 16 + rb;
#pragma unroll
    for (int rr2 = 0; rr2 < 4; ++rr2) {
      long gm = gm0 + rr2;
      if (gm < N_VERT) {
#pragma unroll
        for (int n = 0; n < 4; ++n) {
          long gn = tN + w * 64 + n * 16 + la;
          out[gm * NCOL + gn] = acc[m][n][rr2] + bv[n];
        }
      }
    }
  }
}

extern "C" void kernel_launch(void* const* d_in, const int* in_sizes, int n_in,
                              void* d_out, int out_size, void* d_ws, size_t ws_size,
                              hipStream_t stream) {
  const float* x    = (const float*)d_in[0];
  const float* F    = (const float*)d_in[1];
  const float* W    = (const float*)d_in[2];
  const float* bias = (const float*)d_in[3];
  float* out = (float*)d_out;

  const size_t fbB = (size_t)MPAD * KPAD * 2;
  const size_t htB = (size_t)NCOL * KPAD * 2;
  if (ws_size < fbB + htB) return;

  unsigned short* Fb = (unsigned short*)d_ws;
  unsigned short* Ht = (unsigned short*)((char*)d_ws + fbB);

  prep <<<dim3(G1_BLOCKS + CVT_BLOCKS), 256, 0, stream>>>(x, W, F, Ht, Fb);
  gemm2<<<dim3(1920),                   256, 0, stream>>>(Fb, Ht, bias, out);
}

// Round 4
// 796.436 us; speedup vs baseline: 1.1824x; 1.1824x over previous
//
#include <hip/hip_runtime.h>

// Problem constants
#define N_VERT 5000
#define NCOL   12288      // B*T*C_OUT reinterpreted columns
#define KPAD   5056       // 158*32: K padded (zero-filled)
#define MPAD   5120       // 40*128: M padded

#define G1_BLOCKS  15168  // 79*192 gemm1 blocks
#define CVT_BLOCKS 25280  // MPAD*(KPAD/4)/256

typedef float          f32x4  __attribute__((ext_vector_type(4)));
typedef unsigned short u16x4  __attribute__((ext_vector_type(4)));
typedef __bf16         bf16x8 __attribute__((ext_vector_type(8)));

__device__ __forceinline__ unsigned short f2bf(float f) {
  unsigned int u = __builtin_bit_cast(unsigned int, f);
  u += 0x7fffu + ((u >> 16) & 1u);   // RNE
  return (unsigned short)(u >> 16);
}

__device__ __forceinline__ void async16(const unsigned short* g, unsigned short* l) {
  __builtin_amdgcn_global_load_lds(
      (const __attribute__((address_space(1))) unsigned int*)g,
      (__attribute__((address_space(3))) unsigned int*)l, 16, 0, 0);
}

// ---------------------------------------------------------------------------
// Kernel P (merged prep): blocks [0, G1_BLOCKS) run GEMM1 (x@W -> Ht = H^T,
// bf16); blocks [G1_BLOCKS, +CVT_BLOCKS) convert F -> Fb bf16 [MPAD][KPAD].
// ---------------------------------------------------------------------------
__global__ __launch_bounds__(256) void prep(const float* __restrict__ x,
                                            const float* __restrict__ W,
                                            const float* __restrict__ F,
                                            unsigned short* __restrict__ Ht,
                                            unsigned short* __restrict__ Fb) {
  __shared__ float xt[64][68];
  __shared__ float Wl[64][68];
  const int tid = threadIdx.x;

  if (blockIdx.x >= G1_BLOCKS) {
    int idx = (blockIdx.x - G1_BLOCKS) * 256 + tid;
    int row = idx / (KPAD / 4);
    int c4  = (idx % (KPAD / 4)) * 4;
    u16x4 o;
    if (row < N_VERT && c4 < N_VERT) {
      f32x4 v = *(const f32x4*)(F + (long)row * N_VERT + c4);
      o.x = f2bf(v.x); o.y = f2bf(v.y); o.z = f2bf(v.z); o.w = f2bf(v.w);
    } else {
      o.x = 0; o.y = 0; o.z = 0; o.w = 0;
    }
    *(u16x4*)(Fb + (long)row * KPAD + c4) = o;
    return;
  }

  const int utile = blockIdx.x % 79;   // 0..78
  const int rr    = blockIdx.x / 79;   // 0..191

  for (int i = tid; i < 4096; i += 256) Wl[i >> 6][i & 63] = W[i];
  {
    int rowu = tid >> 2;
    int cb   = (tid & 3) * 16;
    long u   = (long)utile * 64 + rowu;
    bool valid = (u < N_VERT);
    const float* src = x + (u * 192 + rr) * 64;
#pragma unroll
    for (int q = 0; q < 4; ++q) {
      int col = cb + q * 4;
      f32x4 v = {0.f, 0.f, 0.f, 0.f};
      if (valid) v = *(const f32x4*)(src + col);
      xt[col + 0][rowu] = v.x;
      xt[col + 1][rowu] = v.y;
      xt[col + 2][rowu] = v.z;
      xt[col + 3][rowu] = v.w;
    }
  }
  __syncthreads();

  const int ul0 = (tid & 15) * 4;
  const int j0  = (tid >> 4) * 4;
  float acc[4][4] = {};
#pragma unroll 8
  for (int c = 0; c < 64; ++c) {
    f32x4 xv = *(const f32x4*)&xt[c][ul0];
    f32x4 wv = *(const f32x4*)&Wl[c][j0];
#pragma unroll
    for (int a = 0; a < 4; ++a)
#pragma unroll
      for (int b = 0; b < 4; ++b) acc[a][b] += xv[a] * wv[b];
  }

  long ug = (long)utile * 64 + ul0;
#pragma unroll
  for (int b = 0; b < 4; ++b) {
    long rowh = (long)rr * 64 + (j0 + b);
    u16x4 o = {f2bf(acc[0][b]), f2bf(acc[1][b]), f2bf(acc[2][b]), f2bf(acc[3][b])};
    *(u16x4*)(Ht + rowh * KPAD + ug) = o;
  }
}

// ---------------------------------------------------------------------------
// Kernel 3: GEMM2  agg = F @ H (+bias).
// 128x256 tile, BK=32, 256 threads (4 waves, 1M x 4N), LDS 48KiB ->
// 2 co-resident blocks/CU = two independent barrier domains per SIMD
// (one block's barrier/vmcnt stalls overlap the other's MFMA).
// R4 fixes vs R3 (which had the right structure but two layout bugs):
//  (1) chunk swizzle slot' = chunk ^ ((row>>1)&3) within each 64B row:
//      lanes 0-15 of a fragment read now hit 2 lanes per 4-bank group
//      (free 2-way) instead of 8-way. Staging keeps linear LDS dest; the
//      XOR is baked into the per-lane GLOBAL source address (both-sides
//      pattern). All staging rows == l>>2 (mod 16) and all fragment rows
//      == la (mod 16), offsets multiple of 16 -> XOR term is a per-lane
//      constant on each side.
//  (2) XCD map: xcd=bid&7, j=bid>>3, mg=j%5, n=j/5; tM=(xcd+8*mg)*128,
//      tN=n*256. The 40 consumers of each B tile (8 xcd x 5 mg) are
//      dispatched at the same j -> concurrent -> B streams from HBM once
//      (124 MB); A (49 MB) L3-resident.
// Schedule (3-phase, R0-verified invariants, halved for BK=32):
//  PH0: read afL(m0..3) + bb[2..3](t); 16 MFMA afL x bb[0..3]; bar
//  PH1: read afH(m4..7); stage B(t+2); 8 MFMA afH x bb[0..1]; bar
//  PH2: stage A(t+2); vmcnt(6); bar; cross-read bb[0..1](t+1); 8 MFMA
// Per wave/tile: 12 ds_read_b128, 32 MFMA, 6 DMA loads.
// ---------------------------------------------------------------------------
__global__ __launch_bounds__(256, 2) void gemm2(const unsigned short* __restrict__ A,
                                                const unsigned short* __restrict__ Bt,
                                                const float* __restrict__ bias,
                                                float* __restrict__ out) {
  __shared__ __align__(16) unsigned short smem[24576];   // 49152 B = A 8K + B 16K, x2 buf
  char* sm = (char*)smem;

  const int tid = threadIdx.x;
  const int l   = tid & 63;
  const int w   = tid >> 6;        // wave 0..3 = N-quarter
  const int la  = l & 15;

  // XCD map: concurrent blocks share B tiles across all 8 XCDs (fix #2)
  const int xcd = blockIdx.x & 7;
  const int j   = blockIdx.x >> 3;     // 0..239
  const int mg  = j % 5;
  const int nt  = j / 5;               // 0..47
  const long tM = (long)(xcd + 8 * mg) * 128;
  const long tN = (long)nt * 256;

  // --- staging source: lane covers row l>>2, chunk slot l&3; source chunk
  //     pre-swizzled so LDS slot s of row r holds global chunk s^((r>>1)&3).
  const int sChunk = (l & 3) ^ ((l >> 3) & 3);
  const unsigned short* gA2 = A  + (tM + (l >> 2)) * (size_t)KPAD + sChunk * 8;
  const unsigned short* gB2 = Bt + (tN + (l >> 2)) * (size_t)KPAD + sChunk * 8;

  // A region [0,8192): 128 rows x 64B. B region [8192,24576): 256 rows x 64B.
  auto stageA = [&](int bufB, const unsigned short* g) {
    async16(g + (size_t)(w * 16)      * KPAD, (unsigned short*)(sm + bufB + w * 1024));
    async16(g + (size_t)(w * 16 + 64) * KPAD, (unsigned short*)(sm + bufB + w * 1024 + 4096));
  };
  auto stageB = [&](int bufB, const unsigned short* g) {
#pragma unroll
    for (int q = 0; q < 4; ++q)
      async16(g + (size_t)(w * 16 + q * 64) * KPAD,
              (unsigned short*)(sm + bufB + 8192 + w * 1024 + q * 4096));
  };

  // --- fragment read base: row la, chunk (l>>4) ^ ((la>>1)&3)  (fix #1) ---
  const int lofs = la * 64 + (((l >> 4) ^ ((la >> 1) & 3)) << 4);
  const char* pA[2] = { sm + lofs,                   sm + 24576 + lofs };
  const char* pB[2] = { sm + 8192 + w * 4096 + lofs, sm + 24576 + 8192 + w * 4096 + lofs };

  f32x4  acc[8][4] = {};
  bf16x8 af[4], bb[4];

#define MM(MBASE, NLO, NHI)                                                   \
  __builtin_amdgcn_s_setprio(1);                                             \
  _Pragma("unroll")                                                          \
  for (int m = 0; m < 4; ++m)                                                \
    _Pragma("unroll")                                                        \
    for (int n = (NLO); n < (NHI); ++n)                                      \
      acc[(MBASE) + m][n] = __builtin_amdgcn_mfma_f32_16x16x32_bf16(         \
          af[m], bb[n], acc[(MBASE) + m][n], 0, 0, 0);                       \
  __builtin_amdgcn_s_setprio(0);

  // mode: 0 steady; 1 = drain (no stage, vmcnt(0)); 2 = tail (no stage/cross).
  auto tile = [&](int bi, int mode) {
    const int bo = bi * 24576;
    const int ni = bi ^ 1;
    // ==== PH0: read afL + bb[2..3](t); 16 MFMA afL x bb[0..3] ====
#pragma unroll
    for (int m = 0; m < 4; ++m) af[m] = *(const bf16x8*)(pA[bi] + m * 1024);
    bb[2] = *(const bf16x8*)(pB[bi] + 2 * 1024);
    bb[3] = *(const bf16x8*)(pB[bi] + 3 * 1024);
    MM(0, 0, 4)
    __builtin_amdgcn_s_barrier();
    // ==== PH1: read afH; stage B(t+2); 8 MFMA afH x bb[0..1] ====
#pragma unroll
    for (int m = 0; m < 4; ++m) af[m] = *(const bf16x8*)(pA[bi] + (4 + m) * 1024);
    if (mode == 0) { stageB(bo, gB2); gB2 += 32; }
    MM(4, 0, 2)
    __builtin_amdgcn_s_barrier();
    // ==== PH2: stage A(t+2); vmcnt(6); bar; cross-read bb[0..1](t+1); 8 MFMA ====
    if (mode == 0) {
      stageA(bo, gA2); gA2 += 32;
      asm volatile("s_waitcnt vmcnt(6)" ::: "memory");   // t+1 fully landed
    } else if (mode == 1) {
      asm volatile("s_waitcnt vmcnt(0)" ::: "memory");
    }
    __builtin_amdgcn_s_barrier();                         // globalizes vmcnt
    __builtin_amdgcn_sched_barrier(0);                    // pin reads below
    if (mode != 2) {
      bb[0] = *(const bf16x8*)(pB[ni] + 0);               // bb[0..1](t+1)
      bb[1] = *(const bf16x8*)(pB[ni] + 1024);
    }
    MM(4, 2, 4)
    // no trailing barrier: next PH0's reads are covered by this vmcnt+bar
  };

  // ---- prologue: stage t0 -> buf0, t1 -> buf1; pre-read bb[0..1](t0) ----
  stageB(0, gB2);     stageA(0, gA2);     gA2 += 32; gB2 += 32;
  stageB(24576, gB2); stageA(24576, gA2); gA2 += 32; gB2 += 32;  // -> t2
  asm volatile("s_waitcnt vmcnt(6)" ::: "memory");   // t0's 6 loads landed
  __builtin_amdgcn_s_barrier();
  __builtin_amdgcn_sched_barrier(0);
  bb[0] = *(const bf16x8*)(pB[0] + 0);
  bb[1] = *(const bf16x8*)(pB[0] + 1024);

  // ---- main loop: 158 K-tiles (t = 0..157) ----
#pragma unroll 1
  for (int it = 0; it < 77; ++it) {    // t = 0..153
    tile(0, 0);
    tile(1, 0);
  }
  tile(0, 0);   // t=154: stages t156 -> buf0
  tile(1, 0);   // t=155: stages t157 -> buf1
  tile(0, 1);   // t=156: drain, cross-read bb(t157) from buf1
  tile(1, 2);   // t=157: last

#undef MM

  // ---- epilogue: C/D map col=lane&15, row=(lane>>4)*4+reg ----
  float bv[4];
#pragma unroll
  for (int n = 0; n < 4; ++n) bv[n] = bias[n * 16 + la];
  const int rb = (l >> 4) * 4;
#pragma unroll
  for (int m = 0; m < 8; ++m) {
    long gm0 = tM + m * 16 + rb;
#pragma unroll
    for (int rr2 = 0; rr2 < 4; ++rr2) {
      long gm = gm0 + rr2;
      if (gm < N_VERT) {
#pragma unroll
        for (int n = 0; n < 4; ++n) {
          long gn = tN + w * 64 + n * 16 + la;
          out[gm * NCOL + gn] = acc[m][n][rr2] + bv[n];
        }
      }
    }
  }
}

extern "C" void kernel_launch(void* const* d_in, const int* in_sizes, int n_in,
                              void* d_out, int out_size, void* d_ws, size_t ws_size,
                              hipStream_t stream) {
  const float* x    = (const float*)d_in[0];
  const float* F    = (const float*)d_in[1];
  const float* W    = (const float*)d_in[2];
  const float* bias = (const float*)d_in[3];
  float* out = (float*)d_out;

  const size_t fbB = (size_t)MPAD * KPAD * 2;
  const size_t htB = (size_t)NCOL * KPAD * 2;
  if (ws_size < fbB + htB) return;

  unsigned short* Fb = (unsigned short*)d_ws;
  unsigned short* Ht = (unsigned short*)((char*)d_ws + fbB);

  prep <<<dim3(G1_BLOCKS + CVT_BLOCKS), 256, 0, stream>>>(x, W, F, Ht, Fb);
  gemm2<<<dim3(1920),                   256, 0, stream>>>(Fb, Ht, bias, out);
}

// Round 5
// 701.563 us; speedup vs baseline: 1.3423x; 1.1352x over previous
//
#include <hip/hip_runtime.h>

// Problem constants
#define N_VERT 5000
#define NCOL   12288      // B*T*C_OUT reinterpreted columns
#define KPAD   5056       // 158*32: K padded (zero-filled)
#define MPAD   5120       // 20*256: M padded

#define G1_BLOCKS  15168  // 79*192 gemm1 blocks
#define CVT_BLOCKS 25280  // MPAD*(KPAD/4)/256

typedef float          f32x4  __attribute__((ext_vector_type(4)));
typedef unsigned short u16x4  __attribute__((ext_vector_type(4)));
typedef __bf16         bf16x8 __attribute__((ext_vector_type(8)));

__device__ __forceinline__ unsigned short f2bf(float f) {
  unsigned int u = __builtin_bit_cast(unsigned int, f);
  u += 0x7fffu + ((u >> 16) & 1u);   // RNE
  return (unsigned short)(u >> 16);
}

__device__ __forceinline__ void async16(const unsigned short* g, unsigned short* l) {
  __builtin_amdgcn_global_load_lds(
      (const __attribute__((address_space(1))) unsigned int*)g,
      (__attribute__((address_space(3))) unsigned int*)l, 16, 0, 0);
}

// ---------------------------------------------------------------------------
// Kernel P (merged prep): blocks [0, G1_BLOCKS) run GEMM1 (x@W -> Ht = H^T,
// bf16); blocks [G1_BLOCKS, +CVT_BLOCKS) convert F -> Fb bf16 [MPAD][KPAD].
// ---------------------------------------------------------------------------
__global__ __launch_bounds__(256) void prep(const float* __restrict__ x,
                                            const float* __restrict__ W,
                                            const float* __restrict__ F,
                                            unsigned short* __restrict__ Ht,
                                            unsigned short* __restrict__ Fb) {
  __shared__ float xt[64][68];
  __shared__ float Wl[64][68];
  const int tid = threadIdx.x;

  if (blockIdx.x >= G1_BLOCKS) {
    int idx = (blockIdx.x - G1_BLOCKS) * 256 + tid;
    int row = idx / (KPAD / 4);
    int c4  = (idx % (KPAD / 4)) * 4;
    u16x4 o;
    if (row < N_VERT && c4 < N_VERT) {
      f32x4 v = *(const f32x4*)(F + (long)row * N_VERT + c4);
      o.x = f2bf(v.x); o.y = f2bf(v.y); o.z = f2bf(v.z); o.w = f2bf(v.w);
    } else {
      o.x = 0; o.y = 0; o.z = 0; o.w = 0;
    }
    *(u16x4*)(Fb + (long)row * KPAD + c4) = o;
    return;
  }

  const int utile = blockIdx.x % 79;   // 0..78
  const int rr    = blockIdx.x / 79;   // 0..191

  for (int i = tid; i < 4096; i += 256) Wl[i >> 6][i & 63] = W[i];
  {
    int rowu = tid >> 2;
    int cb   = (tid & 3) * 16;
    long u   = (long)utile * 64 + rowu;
    bool valid = (u < N_VERT);
    const float* src = x + (u * 192 + rr) * 64;
#pragma unroll
    for (int q = 0; q < 4; ++q) {
      int col = cb + q * 4;
      f32x4 v = {0.f, 0.f, 0.f, 0.f};
      if (valid) v = *(const f32x4*)(src + col);
      xt[col + 0][rowu] = v.x;
      xt[col + 1][rowu] = v.y;
      xt[col + 2][rowu] = v.z;
      xt[col + 3][rowu] = v.w;
    }
  }
  __syncthreads();

  const int ul0 = (tid & 15) * 4;
  const int j0  = (tid >> 4) * 4;
  float acc[4][4] = {};
#pragma unroll 8
  for (int c = 0; c < 64; ++c) {
    f32x4 xv = *(const f32x4*)&xt[c][ul0];
    f32x4 wv = *(const f32x4*)&Wl[c][j0];
#pragma unroll
    for (int a = 0; a < 4; ++a)
#pragma unroll
      for (int b = 0; b < 4; ++b) acc[a][b] += xv[a] * wv[b];
  }

  long ug = (long)utile * 64 + ul0;
#pragma unroll
  for (int b = 0; b < 4; ++b) {
    long rowh = (long)rr * 64 + (j0 + b);
    u16x4 o = {f2bf(acc[0][b]), f2bf(acc[1][b]), f2bf(acc[2][b]), f2bf(acc[3][b])};
    *(u16x4*)(Ht + rowh * KPAD + ug) = o;
  }
}

// ---------------------------------------------------------------------------
// Kernel 3: GEMM2  agg = F @ H (+bias). 256x256 tile, 8 waves (2Mx4N, wave
// tile 128x64), *** BK=32 with FOUR 32KB LDS buffers and ONE barrier + ONE
// counted vmcnt per K-tile ***.
// Rationale (R5): R0's 3 barriers/tile lockstep all waves into read-burst ->
// MFMA-burst alternation, serializing the per-CU LDS pipe (~285us) and matrix
// pipe (~307us) -> wall ~ sum. Merging each K-step into a single inter-barrier
// region lets waves self-skew (LDS unit serializes the 8 read bursts; early
// waves MFMA while late waves read) -> pipes overlap.
// Region t (buffer b = t&3):  [bar; sched_fence]
//   12 ds_read_b128 (af[0..7], bb[0..3]);  stage(t+3) -> buf (b+3)&3 (4 DMA);
//   32 MFMA;  s_waitcnt vmcnt(8)
// Invariants (per-wave counts, globalized by the barrier):
//   - stage(t+3) targets buf of tile t-1, whose reads were sealed by the
//     barrier that OPENED region t.
//   - vmcnt(8) at end of region t leaves only stage(t+2),(t+3) in flight ->
//     stage(t+1) landed -> next region's reads safe after the barrier.
//   - sched_barrier(0) after each s_barrier pins reads below it (raw
//     s_barrier is not a compiler memory fence).
// Tail: t=155 vmcnt(4), t=156 vmcnt(0), t=157 no stage/sync.
// LDS layout per buffer (32KB): A [0,16K) 256 rows x 64B, B [16K,32K).
// Conflict-free chunk XOR (R4 HW-verified, 0 conflicts): LDS slot s of row r
// holds global chunk s^((r>>1)&3); fragment read chunk (l>>4)^((la>>1)&3).
// Staging keeps linear LDS dest; XOR baked into per-lane global source.
// ---------------------------------------------------------------------------
__global__ __launch_bounds__(512, 2) void gemm2(const unsigned short* __restrict__ A,
                                                const unsigned short* __restrict__ Bt,
                                                const float* __restrict__ bias,
                                                float* __restrict__ out) {
  __shared__ __align__(16) unsigned short smem[65536];   // 131072 B = 4 x 32KB
  char* sm = (char*)smem;

  const int tid = threadIdx.x;
  const int l   = tid & 63;
  const int w   = tid >> 6;        // wave 0..7
  const int wr  = w >> 2;          // 0..1  (M)
  const int wc  = w & 3;           // 0..3  (N)
  const int la  = l & 15;

  // Locality-grouped XCD swizzle (R0-verified: FETCH ~546MB)
  const int xcd = blockIdx.x & 7;
  const int ii  = blockIdx.x >> 3;
  const int gg  = ii / 30;
  const int rmap= ii % 30;
  const long tM = (long)(gg * 5 + (rmap % 5)) * 256;
  const long tN = (long)(xcd * 6 + (rmap / 5)) * 256;

  // --- staging source: lane covers row l>>2 (of each 16-row group), slot l&3;
  //     source chunk = slot ^ ((row>>1)&3) = (l&3) ^ ((l>>3)&3)  (R4-verified)
  const int sChunk = (l & 3) ^ ((l >> 3) & 3);
  const unsigned short* gA2 = A  + (tM + (l >> 2)) * (size_t)KPAD + sChunk * 8;
  const unsigned short* gB2 = Bt + (tN + (l >> 2)) * (size_t)KPAD + sChunk * 8;

  // stage one K-tile (A 16KB + B 16KB) into buffer base bufB; 4 loads/wave.
  // Wave w covers rows w*16 and 128+w*16 of each operand (16 rows/load).
  auto stage = [&](int bufB, const unsigned short* gA, const unsigned short* gB) {
    async16(gA + (size_t)(w * 16)       * KPAD, (unsigned short*)(sm + bufB + w * 1024));
    async16(gA + (size_t)(w * 16 + 128) * KPAD, (unsigned short*)(sm + bufB + 8192 + w * 1024));
    async16(gB + (size_t)(w * 16)       * KPAD, (unsigned short*)(sm + bufB + 16384 + w * 1024));
    async16(gB + (size_t)(w * 16 + 128) * KPAD, (unsigned short*)(sm + bufB + 16384 + 8192 + w * 1024));
  };

  // --- fragment read offsets (conflict-free, R4-verified) ---
  const int chunkoff = ((l >> 4) ^ ((la >> 1) & 3)) << 4;
  const int aOff = (wr * 128 + la) * 64 + chunkoff;          // within A region
  const int bOff = 16384 + (wc * 64 + la) * 64 + chunkoff;   // within buffer

  f32x4  acc[8][4] = {};
  bf16x8 af[8], bb[4];

#define BAR  __builtin_amdgcn_s_barrier()
#define SFEN __builtin_amdgcn_sched_barrier(0)

  // mode: 0 steady (stage, vmcnt 8); 1 vmcnt(4); 2 vmcnt(0); 3 final (none)
  auto region = [&](int b, int mode) {
    const char* bufp = sm + b * 32768;
    // reads: af[0], bb[0..3] first (first MFMA needs them), then af[1..7]
    af[0] = *(const bf16x8*)(bufp + aOff);
#pragma unroll
    for (int n = 0; n < 4; ++n) bb[n] = *(const bf16x8*)(bufp + bOff + n * 1024);
#pragma unroll
    for (int m = 1; m < 8; ++m) af[m] = *(const bf16x8*)(bufp + aOff + m * 1024);
    // stage tile t+3 into buf (b+3)&3 (holds t-1, sealed by opening barrier)
    if (mode == 0) {
      stage(((b + 3) & 3) * 32768, gA2, gB2);
      gA2 += 32; gB2 += 32;
    }
    // MFMA 32 (compiler interleaves with lgkmcnt as frags arrive)
    __builtin_amdgcn_s_setprio(1);
#pragma unroll
    for (int m = 0; m < 8; ++m)
#pragma unroll
      for (int n = 0; n < 4; ++n)
        acc[m][n] = __builtin_amdgcn_mfma_f32_16x16x32_bf16(
            af[m], bb[n], acc[m][n], 0, 0, 0);
    __builtin_amdgcn_s_setprio(0);
    if (mode == 0)      { asm volatile("s_waitcnt vmcnt(8)" ::: "memory"); }
    else if (mode == 1) { asm volatile("s_waitcnt vmcnt(4)" ::: "memory"); }
    else if (mode == 2) { asm volatile("s_waitcnt vmcnt(0)" ::: "memory"); }
    if (mode != 3) { BAR; SFEN; }
  };

  // ---- prologue: stage tiles 0,1,2 -> bufs 0,1,2 ----
  stage(0,     gA2, gB2); gA2 += 32; gB2 += 32;
  stage(32768, gA2, gB2); gA2 += 32; gB2 += 32;
  stage(65536, gA2, gB2); gA2 += 32; gB2 += 32;
  asm volatile("s_waitcnt vmcnt(8)" ::: "memory");   // tile 0 landed
  BAR; SFEN;

  // ---- main loop: 158 K-tiles (t = 0..157), buffer = t&3 ----
#pragma unroll 1
  for (int it = 0; it < 38; ++it) {    // t = 0..151
    region(0, 0); region(1, 0); region(2, 0); region(3, 0);
  }
  region(0, 0);   // t=152 (stages 155 -> buf3)
  region(1, 0);   // t=153 (stages 156 -> buf0)
  region(2, 0);   // t=154 (stages 157 -> buf1)
  region(3, 1);   // t=155 (no stage; vmcnt(4) -> 156 landed)
  region(0, 2);   // t=156 (vmcnt(0) -> 157 landed)
  region(1, 3);   // t=157 (final)

  // ---- epilogue: C/D map col=lane&15, row=(lane>>4)*4+reg ----
  float bv[4];
#pragma unroll
  for (int n = 0; n < 4; ++n) bv[n] = bias[n * 16 + la];
  const int rb = (l >> 4) * 4;
#pragma unroll
  for (int m = 0; m < 8; ++m) {
    long gm0 = tM + wr * 128 + m * 16 + rb;
#pragma unroll
    for (int rr2 = 0; rr2 < 4; ++rr2) {
      long gm = gm0 + rr2;
      if (gm < N_VERT) {
#pragma unroll
        for (int n = 0; n < 4; ++n) {
          long gn = tN + wc * 64 + n * 16 + la;
          out[gm * NCOL + gn] = acc[m][n][rr2] + bv[n];
        }
      }
    }
  }
#undef BAR
#undef SFEN
}

extern "C" void kernel_launch(void* const* d_in, const int* in_sizes, int n_in,
                              void* d_out, int out_size, void* d_ws, size_t ws_size,
                              hipStream_t stream) {
  const float* x    = (const float*)d_in[0];
  const float* F    = (const float*)d_in[1];
  const float* W    = (const float*)d_in[2];
  const float* bias = (const float*)d_in[3];
  float* out = (float*)d_out;

  const size_t fbB = (size_t)MPAD * KPAD * 2;
  const size_t htB = (size_t)NCOL * KPAD * 2;
  if (ws_size < fbB + htB) return;

  unsigned short* Fb = (unsigned short*)d_ws;
  unsigned short* Ht = (unsigned short*)((char*)d_ws + fbB);

  prep <<<dim3(G1_BLOCKS + CVT_BLOCKS), 256, 0, stream>>>(x, W, F, Ht, Fb);
  gemm2<<<dim3(960),                    512, 0, stream>>>(Fb, Ht, bias, out);
}